// Round 9
// baseline (195.616 us; speedup 1.0000x reference)
//
#include <hip/hip_runtime.h>
#include <hip/hip_fp16.h>

// MultiHeadAttention_64106681860559 — round 9:
//  - BK=32 double-buffered (LDS 32/24 KB) -> 3-4 blocks/CU cross-block overlap
//  - Split-K=2 final GEMM (grid 1024, 4/CU) + reduce-bias kernel; f32 partials
//    reuse the dead S buffer
//  - R3-proven 64B-row LDS swizzle (slot ^ (row>>1)&3), XCD block swizzle
//
// Workspace (~128 MB):
//   xb    fp16 [4096][1024] @ 0      | wqkvT fp16 [3072][1024] @ 8 MB
//   qkv   fp16 [4096][3072] @ 14 MB  | S     fp16 [4096][4096] @ 46 MB (dead after
//   P     fp16 [4096][4096] @ 78 MB  |   softmax; reused: part0 @46MB, part1 @62MB f32)
//   vw    fp16 [4096][1024] @ 110 MB | vwT  fp16 [1024][4096] @ 118 MB | woutT @ 126 MB

typedef _Float16 half_t;
typedef _Float16 half8 __attribute__((ext_vector_type(8)));
typedef _Float16 half4 __attribute__((ext_vector_type(4)));
typedef float f32x4 __attribute__((ext_vector_type(4)));

static constexpr int N_TOK = 4096;
static constexpr int LATENT = 1024;
static constexpr int QKVN = 3072;

#define DEVI __device__ __forceinline__

DEVI void gld_lds16(const half_t* g, half_t* l) {
  __builtin_amdgcn_global_load_lds(
      (const __attribute__((address_space(1))) void*)g,
      (__attribute__((address_space(3))) void*)l,
      16, 0, 0);
}

// Stage ROWS x 32 fp16 tile (64B rows = 4 x 16B slots). Physical slot p of row r
// holds logical slot p ^ ((r>>1)&3): pre-swizzled global source, linear LDS dest
// (rule 21). Proven 0-conflict in R3.
template <int ROWS>
DEVI void stage32(const half_t* __restrict__ g, int ld, half_t* lbase, int tid) {
#pragma unroll
  for (int c = tid; c < ROWS * 4; c += 256) {
    int r = c >> 2;
    int k8 = ((c & 3) ^ ((r >> 1) & 3)) * 8;
    gld_lds16(g + (size_t)r * ld + k8, lbase + c * 8);
  }
}

// ---------------------------------------------------------------------------
// GEMM: C[M][N] = A[M][K] @ B^T, B stored [N][K]. BMxBN tile, 4 waves as 2x2,
// BK=32 double-buffered, one barrier per K-tile. gridDim.z = split-K slices;
// slice z reads K range [z*K, (z+1)*K) and writes partial z (MODE 2).
// MODE 0: +bias, cols<1024 scaled 0.125, fp16 out (qkv)
// MODE 1: fp16 out (scores / vw)
// MODE 2: f32 out, no bias, z-sliced partials (split-K)
// ---------------------------------------------------------------------------
template <int BM, int BN, int MODE>
__launch_bounds__(256, 4)
__global__ void gemm_mfma(const half_t* __restrict__ A, int lda,
                          const half_t* __restrict__ B, int ldb,
                          void* __restrict__ Cout, int ldc,
                          const float* __restrict__ bias, int K) {
  constexpr int MF = BM / 32;
  constexpr int NF = BN / 32;
  __shared__ half_t At[2][BM * 32];
  __shared__ half_t Bt[2][BN * 32];

  const int tid = threadIdx.x;
  const int lane = tid & 63;
  const int wid = tid >> 6;

  // XCD-aware bijective remap within each z-slice (grids are multiples of 8).
  const int nx = gridDim.x;
  const int nwg = nx * gridDim.y;
  const int bid = blockIdx.y * nx + blockIdx.x;
  const int cpx = nwg >> 3;
  const int swz = (bid & 7) * cpx + (bid >> 3);
  const int rowBlk = (swz / nx) * BM;
  const int colBlk = (swz % nx) * BN;

  const int wr = (wid >> 1) * (BM / 2);
  const int wc = (wid & 1) * (BN / 2);
  const int fr = lane & 15;
  const int fs = lane >> 4;  // logical 16B slot (k-offset fs*8)

  const int kOff = blockIdx.z * K;
  const half_t* Ag = A + (size_t)rowBlk * lda + kOff;
  const half_t* Bg = B + (size_t)colBlk * ldb + kOff;

  f32x4 acc[MF][NF] = {};

  const int NT = K >> 5;
  stage32<BM>(Ag, lda, At[0], tid);
  stage32<BN>(Bg, ldb, Bt[0], tid);
  __syncthreads();

  int cur = 0;
  for (int t = 0; t < NT; ++t) {
    if (t + 1 < NT) {
      stage32<BM>(Ag + (t + 1) * 32, lda, At[cur ^ 1], tid);
      stage32<BN>(Bg + (t + 1) * 32, ldb, Bt[cur ^ 1], tid);
    }
    const half_t* Ac = At[cur];
    const half_t* Bc = Bt[cur];
    half8 af[MF], bf[NF];
#pragma unroll
    for (int m = 0; m < MF; ++m) {
      int row = wr + m * 16 + fr;
      af[m] = *(const half8*)(Ac + row * 32 + ((fs ^ ((row >> 1) & 3)) * 8));
    }
#pragma unroll
    for (int n = 0; n < NF; ++n) {
      int row = wc + n * 16 + fr;
      bf[n] = *(const half8*)(Bc + row * 32 + ((fs ^ ((row >> 1) & 3)) * 8));
    }
#pragma unroll
    for (int m = 0; m < MF; ++m)
#pragma unroll
      for (int n = 0; n < NF; ++n)
        acc[m][n] = __builtin_amdgcn_mfma_f32_16x16x32_f16(af[m], bf[n], acc[m][n], 0, 0, 0);
    __syncthreads();  // drains vmcnt (stage landed) + releases buf[cur] readers
    cur ^= 1;
  }

  // Epilogue. C/D mapping: col = lane&15, row = (lane>>4)*4 + j.
  const size_t zoff = (MODE == 2) ? (size_t)blockIdx.z * N_TOK * ldc : 0;
#pragma unroll
  for (int m = 0; m < MF; ++m) {
#pragma unroll
    for (int n = 0; n < NF; ++n) {
#pragma unroll
      for (int j = 0; j < 4; ++j) {
        int row = rowBlk + wr + m * 16 + (lane >> 4) * 4 + j;
        int col = colBlk + wc + n * 16 + fr;
        float v = acc[m][n][j];
        if (MODE == 0) {
          v += bias[col];
          if (col < 1024) v *= 0.125f;  // fold 1/sqrt(DK) into q
          ((half_t*)Cout)[(size_t)row * ldc + col] = (half_t)v;
        } else if (MODE == 1) {
          ((half_t*)Cout)[(size_t)row * ldc + col] = (half_t)v;
        } else {
          ((float*)Cout)[zoff + (size_t)row * ldc + col] = v;
        }
      }
    }
  }
}

// ---------------------------------------------------------------------------
// Split-K reduce: out = p0 + p1 + bias (f32, 4096x1024). float4 per thread.
// ---------------------------------------------------------------------------
__launch_bounds__(256)
__global__ void reduce_bias(const float* __restrict__ p0, const float* __restrict__ p1,
                            const float* __restrict__ bias, float* __restrict__ out) {
  int i = blockIdx.x * 256 + threadIdx.x;  // float4 index
  float4 a = ((const float4*)p0)[i];
  float4 b = ((const float4*)p1)[i];
  float4 c = ((const float4*)bias)[i & 255];  // 1024 cols = 256 float4s
  float4 r;
  r.x = a.x + b.x + c.x; r.y = a.y + b.y + c.y;
  r.z = a.z + b.z + c.z; r.w = a.w + b.w + c.w;
  ((float4*)out)[i] = r;
}

// ---------------------------------------------------------------------------
// Row softmax: S fp16 [4096][4096] -> P fp16. One block (256 thr) per row.
// ---------------------------------------------------------------------------
__launch_bounds__(256)
__global__ void softmax_rows(const half_t* __restrict__ S, half_t* __restrict__ P) {
  const int row = blockIdx.x;
  const int t = threadIdx.x;
  const half8* s8 = (const half8*)(S + (size_t)row * N_TOK);

  half8 v[2];
  float lmax = -1e30f;
#pragma unroll
  for (int i = 0; i < 2; ++i) {
    v[i] = s8[t + i * 256];
#pragma unroll
    for (int j = 0; j < 8; ++j) lmax = fmaxf(lmax, (float)v[i][j]);
  }
#pragma unroll
  for (int off = 32; off; off >>= 1) lmax = fmaxf(lmax, __shfl_xor(lmax, off));

  __shared__ float redm[4];
  __shared__ float reds[4];
  if ((t & 63) == 0) redm[t >> 6] = lmax;
  __syncthreads();
  lmax = fmaxf(fmaxf(redm[0], redm[1]), fmaxf(redm[2], redm[3]));

  float e[16];
  float lsum = 0.f;
#pragma unroll
  for (int i = 0; i < 2; ++i)
#pragma unroll
    for (int j = 0; j < 8; ++j) {
      float ev = __expf((float)v[i][j] - lmax);
      e[i * 8 + j] = ev;
      lsum += ev;
    }
#pragma unroll
  for (int off = 32; off; off >>= 1) lsum += __shfl_xor(lsum, off);
  if ((t & 63) == 0) reds[t >> 6] = lsum;
  __syncthreads();
  float inv = 1.f / (reds[0] + reds[1] + reds[2] + reds[3]);

  half8* p8 = (half8*)(P + (size_t)row * N_TOK);
#pragma unroll
  for (int i = 0; i < 2; ++i) {
    half8 h;
#pragma unroll
    for (int j = 0; j < 8; ++j) h[j] = (half_t)(e[i * 8 + j] * inv);
    p8[t + i * 256] = h;
  }
}

// ---------------------------------------------------------------------------
// Transpose [R][C] (row stride ldin) -> fp16 [C][R] (row stride ldout).
// ---------------------------------------------------------------------------
template <typename TI>
__global__ void transpose_to_f16(const TI* __restrict__ in, int ldin,
                                 half_t* __restrict__ out, int ldout) {
  __shared__ float tile[32][33];
  const int cb = blockIdx.x * 32;
  const int rb = blockIdx.y * 32;
  const int tx = threadIdx.x;
#pragma unroll
  for (int i = threadIdx.y; i < 32; i += 8)
    tile[i][tx] = (float)in[(size_t)(rb + i) * ldin + cb + tx];
  __syncthreads();
#pragma unroll
  for (int i = threadIdx.y; i < 32; i += 8)
    out[(size_t)(cb + i) * ldout + rb + tx] = (half_t)tile[tx][i];
}

__global__ void cvt_f32_f16(const float* __restrict__ in, half_t* __restrict__ out) {
  int i = blockIdx.x * 256 + threadIdx.x;  // one float4 per thread
  float4 v = ((const float4*)in)[i];
  half4 h;
  h[0] = (half_t)v.x; h[1] = (half_t)v.y; h[2] = (half_t)v.z; h[3] = (half_t)v.w;
  ((half4*)out)[i] = h;
}

extern "C" void kernel_launch(void* const* d_in, const int* in_sizes, int n_in,
                              void* d_out, int out_size, void* d_ws, size_t ws_size,
                              hipStream_t stream) {
  const float* x = (const float*)d_in[0];
  const float* w_qkv = (const float*)d_in[1];
  const float* b_qkv = (const float*)d_in[2];
  const float* w_out = (const float*)d_in[3];
  const float* b_out = (const float*)d_in[4];
  float* out = (float*)d_out;

  char* ws = (char*)d_ws;
  half_t* xb    = (half_t*)(ws);
  half_t* wqkvT = (half_t*)(ws + ((size_t)8 << 20));
  half_t* qkv   = (half_t*)(ws + ((size_t)14 << 20));
  half_t* S     = (half_t*)(ws + ((size_t)46 << 20));
  half_t* P     = (half_t*)(ws + ((size_t)78 << 20));
  half_t* vw    = (half_t*)(ws + ((size_t)110 << 20));
  half_t* vwT   = (half_t*)(ws + ((size_t)118 << 20));
  half_t* woutT = (half_t*)(ws + ((size_t)126 << 20));
  float*  part0 = (float*)(ws + ((size_t)46 << 20));  // S dead after softmax
  float*  part1 = part0 + (size_t)N_TOK * LATENT;

  dim3 tb(32, 8);

  // 1. x -> fp16
  cvt_f32_f16<<<(N_TOK * LATENT) / (256 * 4), 256, 0, stream>>>(x, xb);
  // 2. w_qkv [1024][3072] -> wqkvT [3072][1024] fp16
  transpose_to_f16<float><<<dim3(QKVN / 32, LATENT / 32), tb, 0, stream>>>(w_qkv, QKVN, wqkvT, LATENT);
  // 3. w_out [1024][1024] -> woutT fp16
  transpose_to_f16<float><<<dim3(LATENT / 32, LATENT / 32), tb, 0, stream>>>(w_out, LATENT, woutT, LATENT);
  // 4. qkv = x @ w_qkv + b (q scaled 0.125), fp16  (768 blocks, 3/CU)
  gemm_mfma<128, 128, 0><<<dim3(QKVN / 128, N_TOK / 128), 256, 0, stream>>>(
      xb, LATENT, wqkvT, LATENT, qkv, QKVN, b_qkv, LATENT);
  // 5. vw = v @ w_out, fp16  (512 blocks)
  gemm_mfma<128, 64, 1><<<dim3(LATENT / 64, N_TOK / 128), 256, 0, stream>>>(
      qkv + 2 * LATENT, QKVN, woutT, LATENT, vw, LATENT, nullptr, LATENT);
  // 6. vw -> vwT [1024][4096]
  transpose_to_f16<half_t><<<dim3(LATENT / 32, N_TOK / 32), tb, 0, stream>>>(
      vw, LATENT, vwT, N_TOK);
  // 7. S = q' @ k^T, fp16  (1024 blocks, 4/CU)
  gemm_mfma<128, 128, 1><<<dim3(N_TOK / 128, N_TOK / 128), 256, 0, stream>>>(
      qkv, QKVN, qkv + LATENT, QKVN, S, N_TOK, nullptr, LATENT);
  // 8. P = softmax rows (fp16)
  softmax_rows<<<N_TOK, 256, 0, stream>>>(S, P);
  // 9. partials = P @ vwT, split-K=2  (2x512 blocks, 4/CU)
  gemm_mfma<128, 64, 2><<<dim3(LATENT / 64, N_TOK / 128, 2), 256, 0, stream>>>(
      P, N_TOK, vwT, N_TOK, part0, LATENT, nullptr, 2048);
  // 10. out = part0 + part1 + b_out
  reduce_bias<<<(N_TOK * LATENT) / (256 * 4), 256, 0, stream>>>(part0, part1, b_out, out);
}

// Round 10
// 193.845 us; speedup vs baseline: 1.0091x; 1.0091x over previous
//
#include <hip/hip_runtime.h>
#include <hip/hip_fp16.h>

// MultiHeadAttention_64106681860559 — round 10:
//  LDS-BW is the measured wall (~26 TB/s read-side; all GEMMs on that line).
//  - Wave tile 64x64 -> 128x64 (MF=8,NF=4): LDS KB/MFMA 0.75 -> 0.375
//  - Block 256x128, BK=32 dbuf (48 KB LDS, 2 blocks/CU)
//  - Final GEMM split-K=4 (grid 512); f32 partials in dead qkv/S region
//  - vwT computed directly as gemm(woutT, v) — vw buffer + transpose deleted
//
// Workspace (~128 MB):
//   xb    fp16 [4096][1024] @ 0      | wqkvT fp16 [3072][1024] @ 8 MB
//   qkv   fp16 [4096][3072] @ 14 MB  | S     fp16 [4096][4096] @ 46 MB
//   P     fp16 [4096][4096] @ 78 MB  | vwT   fp16 [1024][4096] @ 118 MB
//   woutT fp16 [1024][1024] @ 126 MB | parts f32 4x[4096][1024] @ 14 MB (qkv/S dead)

typedef _Float16 half_t;
typedef _Float16 half8 __attribute__((ext_vector_type(8)));
typedef _Float16 half4 __attribute__((ext_vector_type(4)));
typedef float f32x4 __attribute__((ext_vector_type(4)));

static constexpr int N_TOK = 4096;
static constexpr int LATENT = 1024;
static constexpr int QKVN = 3072;

#define DEVI __device__ __forceinline__

DEVI void gld_lds16(const half_t* g, half_t* l) {
  __builtin_amdgcn_global_load_lds(
      (const __attribute__((address_space(1))) void*)g,
      (__attribute__((address_space(3))) void*)l,
      16, 0, 0);
}

// Stage ROWS x 32 fp16 tile (64B rows = 4 x 16B slots). Physical slot p of row r
// holds logical slot p ^ ((r>>1)&3): pre-swizzled global source, linear LDS dest
// (rule 21). Measured 0-conflict (R3/R9).
template <int ROWS>
DEVI void stage32(const half_t* __restrict__ g, int ld, half_t* lbase, int tid) {
#pragma unroll
  for (int c = tid; c < ROWS * 4; c += 256) {
    int r = c >> 2;
    int k8 = ((c & 3) ^ ((r >> 1) & 3)) * 8;
    gld_lds16(g + (size_t)r * ld + k8, lbase + c * 8);
  }
}

// ---------------------------------------------------------------------------
// GEMM: C[M][N] = A[M][K] @ B^T, B stored [N][K]. BMxBN tile, 4 waves as 2x2
// of (BM/2)x(BN/2); BK=32 double-buffered; one barrier per K-tile.
// gridDim.z = split-K slices (MODE 2): slice z covers K range [z*K,(z+1)*K).
// MODE 0: +bias, cols<1024 scaled 0.125, fp16 out (qkv)
// MODE 1: fp16 out (S / vwT)
// MODE 2: f32 out, z-sliced partials (split-K final)
// ---------------------------------------------------------------------------
template <int BM, int BN, int MODE>
__launch_bounds__(256, 2)
__global__ void gemm_mfma(const half_t* __restrict__ A, int lda,
                          const half_t* __restrict__ B, int ldb,
                          void* __restrict__ Cout, int ldc,
                          const float* __restrict__ bias, int K) {
  constexpr int MF = BM / 32;  // 256 -> 8
  constexpr int NF = BN / 32;  // 128 -> 4
  __shared__ half_t At[2][BM * 32];
  __shared__ half_t Bt[2][BN * 32];

  const int tid = threadIdx.x;
  const int lane = tid & 63;
  const int wid = tid >> 6;

  // XCD-aware bijective remap (all grids used are multiples of 8).
  const int nx = gridDim.x;
  const int nwg = nx * gridDim.y;
  const int bid = blockIdx.y * nx + blockIdx.x;
  const int cpx = nwg >> 3;
  const int swz = (bid & 7) * cpx + (bid >> 3);
  const int rowBlk = (swz / nx) * BM;
  const int colBlk = (swz % nx) * BN;

  const int wr = (wid >> 1) * (BM / 2);
  const int wc = (wid & 1) * (BN / 2);
  const int fr = lane & 15;
  const int fs = lane >> 4;  // logical 16B slot (k-offset fs*8)

  const int kOff = blockIdx.z * K;
  const half_t* Ag = A + (size_t)rowBlk * lda + kOff;
  const half_t* Bg = B + (size_t)colBlk * ldb + kOff;

  f32x4 acc[MF][NF] = {};

  const int NT = K >> 5;
  stage32<BM>(Ag, lda, At[0], tid);
  stage32<BN>(Bg, ldb, Bt[0], tid);
  __syncthreads();

  int cur = 0;
  for (int t = 0; t < NT; ++t) {
    if (t + 1 < NT) {
      stage32<BM>(Ag + (t + 1) * 32, lda, At[cur ^ 1], tid);
      stage32<BN>(Bg + (t + 1) * 32, ldb, Bt[cur ^ 1], tid);
    }
    const half_t* Ac = At[cur];
    const half_t* Bc = Bt[cur];
    half8 af[MF], bf[NF];
#pragma unroll
    for (int m = 0; m < MF; ++m) {
      int row = wr + m * 16 + fr;
      af[m] = *(const half8*)(Ac + row * 32 + ((fs ^ ((row >> 1) & 3)) * 8));
    }
#pragma unroll
    for (int n = 0; n < NF; ++n) {
      int row = wc + n * 16 + fr;
      bf[n] = *(const half8*)(Bc + row * 32 + ((fs ^ ((row >> 1) & 3)) * 8));
    }
#pragma unroll
    for (int m = 0; m < MF; ++m)
#pragma unroll
      for (int n = 0; n < NF; ++n)
        acc[m][n] = __builtin_amdgcn_mfma_f32_16x16x32_f16(af[m], bf[n], acc[m][n], 0, 0, 0);
    __syncthreads();  // drains vmcnt (stage landed) + releases buf[cur] readers
    cur ^= 1;
  }

  // Epilogue. C/D mapping: col = lane&15, row = (lane>>4)*4 + j.
  const size_t zoff = (MODE == 2) ? (size_t)blockIdx.z * N_TOK * ldc : 0;
#pragma unroll
  for (int m = 0; m < MF; ++m) {
#pragma unroll
    for (int n = 0; n < NF; ++n) {
#pragma unroll
      for (int j = 0; j < 4; ++j) {
        int row = rowBlk + wr + m * 16 + (lane >> 4) * 4 + j;
        int col = colBlk + wc + n * 16 + fr;
        float v = acc[m][n][j];
        if (MODE == 0) {
          v += bias[col];
          if (col < 1024) v *= 0.125f;  // fold 1/sqrt(DK) into q
          ((half_t*)Cout)[(size_t)row * ldc + col] = (half_t)v;
        } else if (MODE == 1) {
          ((half_t*)Cout)[(size_t)row * ldc + col] = (half_t)v;
        } else {
          ((float*)Cout)[zoff + (size_t)row * ldc + col] = v;
        }
      }
    }
  }
}

// ---------------------------------------------------------------------------
// Split-K reduce: out = p0+p1+p2+p3 + bias (f32, 4096x1024). float4/thread.
// ---------------------------------------------------------------------------
__launch_bounds__(256)
__global__ void reduce_bias4(const float* __restrict__ p, const float* __restrict__ bias,
                             float* __restrict__ out) {
  int i = blockIdx.x * 256 + threadIdx.x;  // float4 index
  const size_t stride4 = (size_t)N_TOK * LATENT / 4;
  float4 a = ((const float4*)p)[i];
  float4 b = ((const float4*)p)[i + stride4];
  float4 c = ((const float4*)p)[i + 2 * stride4];
  float4 d = ((const float4*)p)[i + 3 * stride4];
  float4 e = ((const float4*)bias)[i & 255];  // 1024 cols = 256 float4s
  float4 r;
  r.x = a.x + b.x + c.x + d.x + e.x;
  r.y = a.y + b.y + c.y + d.y + e.y;
  r.z = a.z + b.z + c.z + d.z + e.z;
  r.w = a.w + b.w + c.w + d.w + e.w;
  ((float4*)out)[i] = r;
}

// ---------------------------------------------------------------------------
// Row softmax: S fp16 [4096][4096] -> P fp16. One block (256 thr) per row.
// ---------------------------------------------------------------------------
__launch_bounds__(256)
__global__ void softmax_rows(const half_t* __restrict__ S, half_t* __restrict__ P) {
  const int row = blockIdx.x;
  const int t = threadIdx.x;
  const half8* s8 = (const half8*)(S + (size_t)row * N_TOK);

  half8 v[2];
  float lmax = -1e30f;
#pragma unroll
  for (int i = 0; i < 2; ++i) {
    v[i] = s8[t + i * 256];
#pragma unroll
    for (int j = 0; j < 8; ++j) lmax = fmaxf(lmax, (float)v[i][j]);
  }
#pragma unroll
  for (int off = 32; off; off >>= 1) lmax = fmaxf(lmax, __shfl_xor(lmax, off));

  __shared__ float redm[4];
  __shared__ float reds[4];
  if ((t & 63) == 0) redm[t >> 6] = lmax;
  __syncthreads();
  lmax = fmaxf(fmaxf(redm[0], redm[1]), fmaxf(redm[2], redm[3]));

  float e[16];
  float lsum = 0.f;
#pragma unroll
  for (int i = 0; i < 2; ++i)
#pragma unroll
    for (int j = 0; j < 8; ++j) {
      float ev = __expf((float)v[i][j] - lmax);
      e[i * 8 + j] = ev;
      lsum += ev;
    }
#pragma unroll
  for (int off = 32; off; off >>= 1) lsum += __shfl_xor(lsum, off);
  if ((t & 63) == 0) reds[t >> 6] = lsum;
  __syncthreads();
  float inv = 1.f / (reds[0] + reds[1] + reds[2] + reds[3]);

  half8* p8 = (half8*)(P + (size_t)row * N_TOK);
#pragma unroll
  for (int i = 0; i < 2; ++i) {
    half8 h;
#pragma unroll
    for (int j = 0; j < 8; ++j) h[j] = (half_t)(e[i * 8 + j] * inv);
    p8[t + i * 256] = h;
  }
}

// ---------------------------------------------------------------------------
// Transpose [R][C] (row stride ldin) -> fp16 [C][R] (row stride ldout).
// ---------------------------------------------------------------------------
template <typename TI>
__global__ void transpose_to_f16(const TI* __restrict__ in, int ldin,
                                 half_t* __restrict__ out, int ldout) {
  __shared__ float tile[32][33];
  const int cb = blockIdx.x * 32;
  const int rb = blockIdx.y * 32;
  const int tx = threadIdx.x;
#pragma unroll
  for (int i = threadIdx.y; i < 32; i += 8)
    tile[i][tx] = (float)in[(size_t)(rb + i) * ldin + cb + tx];
  __syncthreads();
#pragma unroll
  for (int i = threadIdx.y; i < 32; i += 8)
    out[(size_t)(cb + i) * ldout + rb + tx] = (half_t)tile[tx][i];
}

__global__ void cvt_f32_f16(const float* __restrict__ in, half_t* __restrict__ out) {
  int i = blockIdx.x * 256 + threadIdx.x;  // one float4 per thread
  float4 v = ((const float4*)in)[i];
  half4 h;
  h[0] = (half_t)v.x; h[1] = (half_t)v.y; h[2] = (half_t)v.z; h[3] = (half_t)v.w;
  ((half4*)out)[i] = h;
}

extern "C" void kernel_launch(void* const* d_in, const int* in_sizes, int n_in,
                              void* d_out, int out_size, void* d_ws, size_t ws_size,
                              hipStream_t stream) {
  const float* x = (const float*)d_in[0];
  const float* w_qkv = (const float*)d_in[1];
  const float* b_qkv = (const float*)d_in[2];
  const float* w_out = (const float*)d_in[3];
  const float* b_out = (const float*)d_in[4];
  float* out = (float*)d_out;

  char* ws = (char*)d_ws;
  half_t* xb    = (half_t*)(ws);
  half_t* wqkvT = (half_t*)(ws + ((size_t)8 << 20));
  half_t* qkv   = (half_t*)(ws + ((size_t)14 << 20));
  half_t* S     = (half_t*)(ws + ((size_t)46 << 20));
  half_t* P     = (half_t*)(ws + ((size_t)78 << 20));
  half_t* vwT   = (half_t*)(ws + ((size_t)118 << 20));
  half_t* woutT = (half_t*)(ws + ((size_t)126 << 20));
  float*  parts = (float*)(ws + ((size_t)14 << 20));  // qkv+S dead by step 8; 64 MB

  dim3 tb(32, 8);

  // 1. x -> fp16
  cvt_f32_f16<<<(N_TOK * LATENT) / (256 * 4), 256, 0, stream>>>(x, xb);
  // 2. w_qkv [1024][3072] -> wqkvT [3072][1024] fp16
  transpose_to_f16<float><<<dim3(QKVN / 32, LATENT / 32), tb, 0, stream>>>(w_qkv, QKVN, wqkvT, LATENT);
  // 3. w_out [1024][1024] -> woutT fp16
  transpose_to_f16<float><<<dim3(LATENT / 32, LATENT / 32), tb, 0, stream>>>(w_out, LATENT, woutT, LATENT);
  // 4. qkv = x @ w_qkv + b (q scaled 0.125), fp16  (384 blocks @ 256x128)
  gemm_mfma<256, 128, 0><<<dim3(QKVN / 128, N_TOK / 256), 256, 0, stream>>>(
      xb, LATENT, wqkvT, LATENT, qkv, QKVN, b_qkv, LATENT);
  // 5. vwT[i][j] = sum_k woutT[i][k] * v[j][k]  (M=1024, N=4096; 256 blocks @ 128x128)
  gemm_mfma<128, 128, 1><<<dim3(N_TOK / 128, LATENT / 128), 256, 0, stream>>>(
      woutT, LATENT, qkv + 2 * LATENT, QKVN, vwT, N_TOK, nullptr, LATENT);
  // 6. S = q' @ k^T, fp16  (512 blocks @ 256x128)
  gemm_mfma<256, 128, 1><<<dim3(N_TOK / 128, N_TOK / 256), 256, 0, stream>>>(
      qkv, QKVN, qkv + LATENT, QKVN, S, N_TOK, nullptr, LATENT);
  // 7. P = softmax rows (fp16)
  softmax_rows<<<N_TOK, 256, 0, stream>>>(S, P);
  // 8. parts = P @ vwT, split-K=4  (4x128 blocks @ 256x128)
  gemm_mfma<256, 128, 2><<<dim3(LATENT / 128, N_TOK / 256, 4), 256, 0, stream>>>(
      P, N_TOK, vwT, N_TOK, parts, LATENT, nullptr, 1024);
  // 9. out = sum(parts) + b_out
  reduce_bias4<<<(N_TOK * LATENT) / (256 * 4), 256, 0, stream>>>(parts, b_out, out);
}

// Round 11
// 184.729 us; speedup vs baseline: 1.0589x; 1.0493x over previous
//
#include <hip/hip_runtime.h>
#include <hip/hip_fp16.h>

// MultiHeadAttention_64106681860559 — round 11: 8-phase 256x256 GEMM (T3+T4+T5)
// for qkv / S / final; counted vmcnt(4), raw s_barrier, setprio around MFMA.
// 2-phase 128x128 kept for the small vwT GEMM. Layouts/swizzle as R10 (0-conflict).
//
// Workspace (~128 MB):
//   xb fp16 [4096][1024] @0 | wqkvT fp16 [3072][1024] @8M | qkv fp16 [4096][3072] @14M
//   S fp16 [4096][4096] @46M | P fp16 [4096][4096] @78M | vwT fp16 [1024][4096] @118M
//   woutT fp16 [1024][1024] @126M | parts f32 4x[4096][1024] @14M (qkv+S dead)

typedef _Float16 half_t;
typedef _Float16 half8 __attribute__((ext_vector_type(8)));
typedef _Float16 half4 __attribute__((ext_vector_type(4)));
typedef float f32x4 __attribute__((ext_vector_type(4)));

static constexpr int N_TOK = 4096;
static constexpr int LATENT = 1024;
static constexpr int QKVN = 3072;

#define DEVI __device__ __forceinline__

DEVI void gld_lds16(const half_t* g, half_t* l) {
  __builtin_amdgcn_global_load_lds(
      (const __attribute__((address_space(1))) void*)g,
      (__attribute__((address_space(3))) void*)l,
      16, 0, 0);
}

DEVI f32x4 MFMA(half8 a, half8 b, f32x4 c) {
  return __builtin_amdgcn_mfma_f32_16x16x32_f16(a, b, c, 0, 0, 0);
}

// ---- 64B-row swizzle (R3/R9-proven, 0 conflicts): phys slot p of row r holds
// logical slot p ^ ((r>>1)&3). Stage pre-swizzles the global source; reads XOR.

// Stage a [256][32] fp16 half-K-tile (1024 x 16B chunks, 512 threads, 2 each).
DEVI void stageH(const half_t* __restrict__ g, int ld, half_t* lbase, int tid) {
#pragma unroll
  for (int i = 0; i < 2; ++i) {
    int c = tid + i * 512;
    int r = c >> 2;
    int k8 = ((c & 3) ^ ((r >> 1) & 3)) * 8;
    gld_lds16(g + (size_t)r * ld + k8, lbase + c * 8);
  }
}

// ---------------------------------------------------------------------------
// 8-phase 256x256 GEMM: C = A[M][K] @ B^T (B stored [N][K]). 512 thr = 8 waves
// (2Mx4N), per-wave 128x64 output. BK=64 as two 32-wide K-halves; per phase:
// {ds_read frags | stage 1 half-tile -> buf^1 | s_barrier | setprio(1) |
//  16 MFMA | setprio(0) | [vmcnt(4) phases 1,3] | s_barrier}.
// MODE 0: +bias, cols<1024 * 0.125, fp16 (qkv) | MODE 1: fp16 (S) |
// MODE 2: f32 z-sliced partials (split-K final)
// ---------------------------------------------------------------------------
template <int MODE>
__launch_bounds__(512, 2)
__global__ void gemm8(const half_t* __restrict__ A, int lda,
                      const half_t* __restrict__ B, int ldb,
                      void* __restrict__ Cout, int ldc,
                      const float* __restrict__ bias, int K) {
  __shared__ half_t Alds[2][2][256 * 32];  // 64 KB
  __shared__ half_t Blds[2][2][256 * 32];  // 64 KB

  const int tid = threadIdx.x;
  const int lane = tid & 63;
  const int wid = tid >> 6;

  // XCD-aware bijective remap (grids are multiples of 8 per z-slice).
  const int nx = gridDim.x;
  const int nwg = nx * gridDim.y;
  const int bid = blockIdx.y * nx + blockIdx.x;
  const int cpx = nwg >> 3;
  const int swz = (bid & 7) * cpx + (bid >> 3);
  const int rowBlk = (swz / nx) * 256;
  const int colBlk = (swz % nx) * 256;

  const int wr = (wid >> 2) * 128;  // 2 wave-rows
  const int wc = (wid & 3) * 64;    // 4 wave-cols
  const int fr = lane & 15;
  const int fs = lane >> 4;

  const int kOff = blockIdx.z * K;
  const half_t* Ag = A + (size_t)rowBlk * lda + kOff;
  const half_t* Bg = B + (size_t)colBlk * ldb + kOff;

  f32x4 acc[8][4] = {};
  const int NT = K >> 6;

  // Prologue: stage tile 0's 4 half-K-tiles; vmcnt(4) -> kh0 pair landed.
  stageH(Ag, lda, Alds[0][0], tid);
  stageH(Bg, ldb, Blds[0][0], tid);
  stageH(Ag + 32, lda, Alds[0][1], tid);
  stageH(Bg + 32, ldb, Blds[0][1], tid);
  asm volatile("s_waitcnt vmcnt(4)" ::: "memory");
  __builtin_amdgcn_s_barrier();

  for (int kt = 0; kt < NT; ++kt) {
    const int b = kt & 1;
    const bool st = (kt + 1 < NT);
    const half_t* A0 = Alds[b][0];
    const half_t* B0 = Blds[b][0];
    const half_t* A1 = Alds[b][1];
    const half_t* B1 = Blds[b][1];
    const half_t* AgN = Ag + (kt + 1) * 64;
    const half_t* BgN = Bg + (kt + 1) * 64;

    half8 af[8], bf[4];

    // ---- phase 0 (kk=0): af[0..7] + bf[0,1]; stage A(kt+1,kh0)
#pragma unroll
    for (int m = 0; m < 8; ++m) {
      int row = wr + m * 16 + fr;
      af[m] = *(const half8*)(A0 + row * 32 + ((fs ^ ((row >> 1) & 3)) * 8));
    }
#pragma unroll
    for (int n = 0; n < 2; ++n) {
      int row = wc + n * 16 + fr;
      bf[n] = *(const half8*)(B0 + row * 32 + ((fs ^ ((row >> 1) & 3)) * 8));
    }
    if (st) stageH(AgN, lda, Alds[b ^ 1][0], tid);
    __builtin_amdgcn_s_barrier();
    __builtin_amdgcn_s_setprio(1);
#pragma unroll
    for (int m = 0; m < 8; ++m) {
      acc[m][0] = MFMA(af[m], bf[0], acc[m][0]);
      acc[m][1] = MFMA(af[m], bf[1], acc[m][1]);
    }
    __builtin_amdgcn_s_setprio(0);
    __builtin_amdgcn_s_barrier();

    // ---- phase 1 (kk=0): bf[2,3]; stage B(kt+1,kh0); vmcnt before barrier
#pragma unroll
    for (int n = 2; n < 4; ++n) {
      int row = wc + n * 16 + fr;
      bf[n] = *(const half8*)(B0 + row * 32 + ((fs ^ ((row >> 1) & 3)) * 8));
    }
    if (st) stageH(BgN, ldb, Blds[b ^ 1][0], tid);
    __builtin_amdgcn_s_barrier();
    __builtin_amdgcn_s_setprio(1);
#pragma unroll
    for (int m = 0; m < 8; ++m) {
      acc[m][2] = MFMA(af[m], bf[2], acc[m][2]);
      acc[m][3] = MFMA(af[m], bf[3], acc[m][3]);
    }
    __builtin_amdgcn_s_setprio(0);
    if (st) asm volatile("s_waitcnt vmcnt(4)" ::: "memory");  // kt's kh1 pair landed
    else    asm volatile("s_waitcnt vmcnt(0)" ::: "memory");  // last tile: drain
    __builtin_amdgcn_s_barrier();

    // ---- phase 2 (kk=1): af[0..7] + bf[0,1]; stage A(kt+1,kh1)
#pragma unroll
    for (int m = 0; m < 8; ++m) {
      int row = wr + m * 16 + fr;
      af[m] = *(const half8*)(A1 + row * 32 + ((fs ^ ((row >> 1) & 3)) * 8));
    }
#pragma unroll
    for (int n = 0; n < 2; ++n) {
      int row = wc + n * 16 + fr;
      bf[n] = *(const half8*)(B1 + row * 32 + ((fs ^ ((row >> 1) & 3)) * 8));
    }
    if (st) stageH(AgN + 32, lda, Alds[b ^ 1][1], tid);
    __builtin_amdgcn_s_barrier();
    __builtin_amdgcn_s_setprio(1);
#pragma unroll
    for (int m = 0; m < 8; ++m) {
      acc[m][0] = MFMA(af[m], bf[0], acc[m][0]);
      acc[m][1] = MFMA(af[m], bf[1], acc[m][1]);
    }
    __builtin_amdgcn_s_setprio(0);
    __builtin_amdgcn_s_barrier();

    // ---- phase 3 (kk=1): bf[2,3]; stage B(kt+1,kh1); vmcnt(4) -> next kh0 pair
#pragma unroll
    for (int n = 2; n < 4; ++n) {
      int row = wc + n * 16 + fr;
      bf[n] = *(const half8*)(B1 + row * 32 + ((fs ^ ((row >> 1) & 3)) * 8));
    }
    if (st) stageH(BgN + 32, ldb, Blds[b ^ 1][1], tid);
    __builtin_amdgcn_s_barrier();
    __builtin_amdgcn_s_setprio(1);
#pragma unroll
    for (int m = 0; m < 8; ++m) {
      acc[m][2] = MFMA(af[m], bf[2], acc[m][2]);
      acc[m][3] = MFMA(af[m], bf[3], acc[m][3]);
    }
    __builtin_amdgcn_s_setprio(0);
    if (st) asm volatile("s_waitcnt vmcnt(4)" ::: "memory");
    __builtin_amdgcn_s_barrier();
  }

  // Epilogue. C/D mapping: col = lane&15, row = (lane>>4)*4 + j.
  const size_t zoff = (MODE == 2) ? (size_t)blockIdx.z * N_TOK * ldc : 0;
#pragma unroll
  for (int m = 0; m < 8; ++m) {
#pragma unroll
    for (int n = 0; n < 4; ++n) {
#pragma unroll
      for (int j = 0; j < 4; ++j) {
        int row = rowBlk + wr + m * 16 + (lane >> 4) * 4 + j;
        int col = colBlk + wc + n * 16 + fr;
        float v = acc[m][n][j];
        if (MODE == 0) {
          v += bias[col];
          if (col < 1024) v *= 0.125f;  // fold 1/sqrt(DK) into q
          ((half_t*)Cout)[(size_t)row * ldc + col] = (half_t)v;
        } else if (MODE == 1) {
          ((half_t*)Cout)[(size_t)row * ldc + col] = (half_t)v;
        } else {
          ((float*)Cout)[zoff + (size_t)row * ldc + col] = v;
        }
      }
    }
  }
}

// ---------------------------------------------------------------------------
// 2-phase 128x128 GEMM (R10 structure) — used for the small vwT GEMM only.
// ---------------------------------------------------------------------------
template <int ROWS>
DEVI void stage32(const half_t* __restrict__ g, int ld, half_t* lbase, int tid) {
#pragma unroll
  for (int c = tid; c < ROWS * 4; c += 256) {
    int r = c >> 2;
    int k8 = ((c & 3) ^ ((r >> 1) & 3)) * 8;
    gld_lds16(g + (size_t)r * ld + k8, lbase + c * 8);
  }
}

__launch_bounds__(256, 2)
__global__ void gemm2(const half_t* __restrict__ A, int lda,
                      const half_t* __restrict__ B, int ldb,
                      half_t* __restrict__ Cout, int ldc, int K) {
  constexpr int BM = 128, BN = 128, MF = 4, NF = 4;
  __shared__ half_t At[2][BM * 32];
  __shared__ half_t Bt[2][BN * 32];

  const int tid = threadIdx.x;
  const int lane = tid & 63;
  const int wid = tid >> 6;

  const int nx = gridDim.x;
  const int nwg = nx * gridDim.y;
  const int bid = blockIdx.y * nx + blockIdx.x;
  const int cpx = nwg >> 3;
  const int swz = (bid & 7) * cpx + (bid >> 3);
  const int rowBlk = (swz / nx) * BM;
  const int colBlk = (swz % nx) * BN;

  const int wr = (wid >> 1) * (BM / 2);
  const int wc = (wid & 1) * (BN / 2);
  const int fr = lane & 15;
  const int fs = lane >> 4;

  const half_t* Ag = A + (size_t)rowBlk * lda;
  const half_t* Bg = B + (size_t)colBlk * ldb;

  f32x4 acc[MF][NF] = {};
  const int NT = K >> 5;
  stage32<BM>(Ag, lda, At[0], tid);
  stage32<BN>(Bg, ldb, Bt[0], tid);
  __syncthreads();

  int cur = 0;
  for (int t = 0; t < NT; ++t) {
    if (t + 1 < NT) {
      stage32<BM>(Ag + (t + 1) * 32, lda, At[cur ^ 1], tid);
      stage32<BN>(Bg + (t + 1) * 32, ldb, Bt[cur ^ 1], tid);
    }
    const half_t* Ac = At[cur];
    const half_t* Bc = Bt[cur];
    half8 af[MF], bf[NF];
#pragma unroll
    for (int m = 0; m < MF; ++m) {
      int row = wr + m * 16 + fr;
      af[m] = *(const half8*)(Ac + row * 32 + ((fs ^ ((row >> 1) & 3)) * 8));
    }
#pragma unroll
    for (int n = 0; n < NF; ++n) {
      int row = wc + n * 16 + fr;
      bf[n] = *(const half8*)(Bc + row * 32 + ((fs ^ ((row >> 1) & 3)) * 8));
    }
#pragma unroll
    for (int m = 0; m < MF; ++m)
#pragma unroll
      for (int n = 0; n < NF; ++n)
        acc[m][n] = MFMA(af[m], bf[n], acc[m][n]);
    __syncthreads();
    cur ^= 1;
  }

#pragma unroll
  for (int m = 0; m < MF; ++m)
#pragma unroll
    for (int n = 0; n < NF; ++n)
#pragma unroll
      for (int j = 0; j < 4; ++j) {
        int row = rowBlk + wr + m * 16 + (lane >> 4) * 4 + j;
        int col = colBlk + wc + n * 16 + fr;
        Cout[(size_t)row * ldc + col] = (half_t)acc[m][n][j];
      }
}

// ---------------------------------------------------------------------------
// Split-K reduce: out = p0+p1+p2+p3 + bias (f32, 4096x1024).
// ---------------------------------------------------------------------------
__launch_bounds__(256)
__global__ void reduce_bias4(const float* __restrict__ p, const float* __restrict__ bias,
                             float* __restrict__ out) {
  int i = blockIdx.x * 256 + threadIdx.x;
  const size_t stride4 = (size_t)N_TOK * LATENT / 4;
  float4 a = ((const float4*)p)[i];
  float4 b = ((const float4*)p)[i + stride4];
  float4 c = ((const float4*)p)[i + 2 * stride4];
  float4 d = ((const float4*)p)[i + 3 * stride4];
  float4 e = ((const float4*)bias)[i & 255];
  float4 r;
  r.x = a.x + b.x + c.x + d.x + e.x;
  r.y = a.y + b.y + c.y + d.y + e.y;
  r.z = a.z + b.z + c.z + d.z + e.z;
  r.w = a.w + b.w + c.w + d.w + e.w;
  ((float4*)out)[i] = r;
}

// ---------------------------------------------------------------------------
// Row softmax: S fp16 [4096][4096] -> P fp16. One block (256 thr) per row.
// ---------------------------------------------------------------------------
__launch_bounds__(256)
__global__ void softmax_rows(const half_t* __restrict__ S, half_t* __restrict__ P) {
  const int row = blockIdx.x;
  const int t = threadIdx.x;
  const half8* s8 = (const half8*)(S + (size_t)row * N_TOK);

  half8 v[2];
  float lmax = -1e30f;
#pragma unroll
  for (int i = 0; i < 2; ++i) {
    v[i] = s8[t + i * 256];
#pragma unroll
    for (int j = 0; j < 8; ++j) lmax = fmaxf(lmax, (float)v[i][j]);
  }
#pragma unroll
  for (int off = 32; off; off >>= 1) lmax = fmaxf(lmax, __shfl_xor(lmax, off));

  __shared__ float redm[4];
  __shared__ float reds[4];
  if ((t & 63) == 0) redm[t >> 6] = lmax;
  __syncthreads();
  lmax = fmaxf(fmaxf(redm[0], redm[1]), fmaxf(redm[2], redm[3]));

  float e[16];
  float lsum = 0.f;
#pragma unroll
  for (int i = 0; i < 2; ++i)
#pragma unroll
    for (int j = 0; j < 8; ++j) {
      float ev = __expf((float)v[i][j] - lmax);
      e[i * 8 + j] = ev;
      lsum += ev;
    }
#pragma unroll
  for (int off = 32; off; off >>= 1) lsum += __shfl_xor(lsum, off);
  if ((t & 63) == 0) reds[t >> 6] = lsum;
  __syncthreads();
  float inv = 1.f / (reds[0] + reds[1] + reds[2] + reds[3]);

  half8* p8 = (half8*)(P + (size_t)row * N_TOK);
#pragma unroll
  for (int i = 0; i < 2; ++i) {
    half8 h;
#pragma unroll
    for (int j = 0; j < 8; ++j) h[j] = (half_t)(e[i * 8 + j] * inv);
    p8[t + i * 256] = h;
  }
}

// ---------------------------------------------------------------------------
// Transpose [R][C] -> fp16 [C][R].
// ---------------------------------------------------------------------------
template <typename TI>
__global__ void transpose_to_f16(const TI* __restrict__ in, int ldin,
                                 half_t* __restrict__ out, int ldout) {
  __shared__ float tile[32][33];
  const int cb = blockIdx.x * 32;
  const int rb = blockIdx.y * 32;
  const int tx = threadIdx.x;
#pragma unroll
  for (int i = threadIdx.y; i < 32; i += 8)
    tile[i][tx] = (float)in[(size_t)(rb + i) * ldin + cb + tx];
  __syncthreads();
#pragma unroll
  for (int i = threadIdx.y; i < 32; i += 8)
    out[(size_t)(cb + i) * ldout + rb + tx] = (half_t)tile[tx][i];
}

__global__ void cvt_f32_f16(const float* __restrict__ in, half_t* __restrict__ out) {
  int i = blockIdx.x * 256 + threadIdx.x;
  float4 v = ((const float4*)in)[i];
  half4 h;
  h[0] = (half_t)v.x; h[1] = (half_t)v.y; h[2] = (half_t)v.z; h[3] = (half_t)v.w;
  ((half4*)out)[i] = h;
}

extern "C" void kernel_launch(void* const* d_in, const int* in_sizes, int n_in,
                              void* d_out, int out_size, void* d_ws, size_t ws_size,
                              hipStream_t stream) {
  const float* x = (const float*)d_in[0];
  const float* w_qkv = (const float*)d_in[1];
  const float* b_qkv = (const float*)d_in[2];
  const float* w_out = (const float*)d_in[3];
  const float* b_out = (const float*)d_in[4];
  float* out = (float*)d_out;

  char* ws = (char*)d_ws;
  half_t* xb    = (half_t*)(ws);
  half_t* wqkvT = (half_t*)(ws + ((size_t)8 << 20));
  half_t* qkv   = (half_t*)(ws + ((size_t)14 << 20));
  half_t* S     = (half_t*)(ws + ((size_t)46 << 20));
  half_t* P     = (half_t*)(ws + ((size_t)78 << 20));
  half_t* vwT   = (half_t*)(ws + ((size_t)118 << 20));
  half_t* woutT = (half_t*)(ws + ((size_t)126 << 20));
  float*  parts = (float*)(ws + ((size_t)14 << 20));  // qkv+S dead by then

  dim3 tb(32, 8);

  // 1. x -> fp16
  cvt_f32_f16<<<(N_TOK * LATENT) / (256 * 4), 256, 0, stream>>>(x, xb);
  // 2. w_qkv -> wqkvT [3072][1024] fp16
  transpose_to_f16<float><<<dim3(QKVN / 32, LATENT / 32), tb, 0, stream>>>(w_qkv, QKVN, wqkvT, LATENT);
  // 3. w_out -> woutT [1024][1024] fp16
  transpose_to_f16<float><<<dim3(LATENT / 32, LATENT / 32), tb, 0, stream>>>(w_out, LATENT, woutT, LATENT);
  // 4. qkv = x @ w_qkv + b (q scaled 0.125)  (192 blocks @ 256x256, 8-phase)
  gemm8<0><<<dim3(QKVN / 256, N_TOK / 256), 512, 0, stream>>>(
      xb, LATENT, wqkvT, LATENT, qkv, QKVN, b_qkv, LATENT);
  // 5. vwT[i][j] = sum_k woutT[i][k] * v[j][k]  (256 blocks @ 128x128, 2-phase)
  gemm2<<<dim3(N_TOK / 128, LATENT / 128), 256, 0, stream>>>(
      woutT, LATENT, qkv + 2 * LATENT, QKVN, vwT, N_TOK, LATENT);
  // 6. S = q' @ k^T  (256 blocks @ 256x256, 8-phase)
  gemm8<1><<<dim3(N_TOK / 256, N_TOK / 256), 512, 0, stream>>>(
      qkv, QKVN, qkv + LATENT, QKVN, S, N_TOK, nullptr, LATENT);
  // 7. P = softmax rows
  softmax_rows<<<N_TOK, 256, 0, stream>>>(S, P);
  // 8. parts = P @ vwT, split-K=4  (4 x 64 blocks @ 256x256, 8-phase)
  gemm8<2><<<dim3(LATENT / 256, N_TOK / 256, 4), 512, 0, stream>>>(
      P, N_TOK, vwT, N_TOK, parts, LATENT, nullptr, 1024);
  // 9. out = sum(parts) + b_out
  reduce_bias4<<<(N_TOK * LATENT) / (256 * 4), 256, 0, stream>>>(parts, b_out, out);
}

// Round 12
// 172.636 us; speedup vs baseline: 1.1331x; 1.0700x over previous
//
#include <hip/hip_runtime.h>
#include <hip/hip_fp16.h>

// MultiHeadAttention_64106681860559 — round 12:
//  - gemm8: 2 long phases per K-tile (32 MFMA, 12 balanced ds_reads, stage A+B
//    per phase) -> half the barriers, longer MFMA clusters for pipe overlap.
//    Uniform counted vmcnt(4) per phase; vmcnt(0) only at the last tile.
//  - Split-K partials in fp16 (halves partial HBM traffic; reduce reads half).
//
// Workspace (~128 MB):
//   xb fp16 [4096][1024] @0 | wqkvT fp16 [3072][1024] @8M | qkv fp16 [4096][3072] @14M
//   S fp16 [4096][4096] @46M | P fp16 [4096][4096] @78M | vwT fp16 [1024][4096] @118M
//   woutT fp16 [1024][1024] @126M | parts fp16 4x[4096][1024] @14M (qkv+S dead)

typedef _Float16 half_t;
typedef _Float16 half8 __attribute__((ext_vector_type(8)));
typedef _Float16 half4 __attribute__((ext_vector_type(4)));
typedef float f32x4 __attribute__((ext_vector_type(4)));

static constexpr int N_TOK = 4096;
static constexpr int LATENT = 1024;
static constexpr int QKVN = 3072;

#define DEVI __device__ __forceinline__

DEVI void gld_lds16(const half_t* g, half_t* l) {
  __builtin_amdgcn_global_load_lds(
      (const __attribute__((address_space(1))) void*)g,
      (__attribute__((address_space(3))) void*)l,
      16, 0, 0);
}

DEVI f32x4 MFMA(half8 a, half8 b, f32x4 c) {
  return __builtin_amdgcn_mfma_f32_16x16x32_f16(a, b, c, 0, 0, 0);
}

// ---- 64B-row swizzle (R3/R9/R11-proven, 0 conflicts): phys slot p of row r
// holds logical slot p ^ ((r>>1)&3). Stage pre-swizzles global source; reads XOR.

// Stage a [256][32] fp16 half-K-tile (1024 x 16B chunks, 512 threads, 2 each).
DEVI void stageH(const half_t* __restrict__ g, int ld, half_t* lbase, int tid) {
#pragma unroll
  for (int i = 0; i < 2; ++i) {
    int c = tid + i * 512;
    int r = c >> 2;
    int k8 = ((c & 3) ^ ((r >> 1) & 3)) * 8;
    gld_lds16(g + (size_t)r * ld + k8, lbase + c * 8);
  }
}

// ---------------------------------------------------------------------------
// 256x256 GEMM, 512 thr = 8 waves (2Mx4N), per-wave 128x64 (acc[8][4]).
// BK=64 as two 32-wide K-halves; TWO phases per K-tile:
//   {12 ds_read frags | stage A+B next-half | BAR | setprio1 | 32 MFMA |
//    setprio0 | vmcnt(4) | BAR}
// MODE 0: +bias, cols<1024 * 0.125, fp16 (qkv) | MODE 1: fp16 (S) |
// MODE 2: fp16 z-sliced partials (split-K final)
// ---------------------------------------------------------------------------
template <int MODE>
__launch_bounds__(512, 2)
__global__ void gemm8(const half_t* __restrict__ A, int lda,
                      const half_t* __restrict__ B, int ldb,
                      void* __restrict__ Cout, int ldc,
                      const float* __restrict__ bias, int K) {
  __shared__ half_t Alds[2][2][256 * 32];  // 64 KB
  __shared__ half_t Blds[2][2][256 * 32];  // 64 KB

  const int tid = threadIdx.x;
  const int lane = tid & 63;
  const int wid = tid >> 6;

  // XCD-aware bijective remap (grids are multiples of 8 per z-slice).
  const int nx = gridDim.x;
  const int nwg = nx * gridDim.y;
  const int bid = blockIdx.y * nx + blockIdx.x;
  const int cpx = nwg >> 3;
  const int swz = (bid & 7) * cpx + (bid >> 3);
  const int rowBlk = (swz / nx) * 256;
  const int colBlk = (swz % nx) * 256;

  const int wr = (wid >> 2) * 128;
  const int wc = (wid & 3) * 64;
  const int fr = lane & 15;
  const int fs = lane >> 4;

  const int kOff = blockIdx.z * K;
  const half_t* Ag = A + (size_t)rowBlk * lda + kOff;
  const half_t* Bg = B + (size_t)colBlk * ldb + kOff;

  f32x4 acc[8][4] = {};
  const int NT = K >> 6;

  // Prologue: stage tile 0 (kh0 then kh1); vmcnt(4) -> kh0 pair landed.
  stageH(Ag, lda, Alds[0][0], tid);
  stageH(Bg, ldb, Blds[0][0], tid);
  stageH(Ag + 32, lda, Alds[0][1], tid);
  stageH(Bg + 32, ldb, Blds[0][1], tid);
  asm volatile("s_waitcnt vmcnt(4)" ::: "memory");
  __builtin_amdgcn_s_barrier();

  for (int kt = 0; kt < NT; ++kt) {
    const int b = kt & 1;
    const bool st = (kt + 1 < NT);
    const half_t* AgN = Ag + (kt + 1) * 64;
    const half_t* BgN = Bg + (kt + 1) * 64;

    half8 af[8], bf[4];

#pragma unroll
    for (int kh = 0; kh < 2; ++kh) {
      const half_t* Ac = Alds[b][kh];
      const half_t* Bc = Blds[b][kh];
      // 12 ds_read_b128 (balanced)
#pragma unroll
      for (int m = 0; m < 8; ++m) {
        int row = wr + m * 16 + fr;
        af[m] = *(const half8*)(Ac + row * 32 + ((fs ^ ((row >> 1) & 3)) * 8));
      }
#pragma unroll
      for (int n = 0; n < 4; ++n) {
        int row = wc + n * 16 + fr;
        bf[n] = *(const half8*)(Bc + row * 32 + ((fs ^ ((row >> 1) & 3)) * 8));
      }
      // stage next tile's same K-half (A+B, 4 ops/thread)
      if (st) {
        stageH(AgN + kh * 32, lda, Alds[b ^ 1][kh], tid);
        stageH(BgN + kh * 32, ldb, Blds[b ^ 1][kh], tid);
      }
      __builtin_amdgcn_s_barrier();
      __builtin_amdgcn_s_setprio(1);
#pragma unroll
      for (int m = 0; m < 8; ++m)
#pragma unroll
        for (int n = 0; n < 4; ++n)
          acc[m][n] = MFMA(af[m], bf[n], acc[m][n]);
      __builtin_amdgcn_s_setprio(0);
      // kh=0: protect this tile's kh1 reads. kh=1: protect next tile's kh0 reads.
      if (st) asm volatile("s_waitcnt vmcnt(4)" ::: "memory");
      else if (kh == 0) asm volatile("s_waitcnt vmcnt(0)" ::: "memory");
      __builtin_amdgcn_s_barrier();
    }
  }

  // Epilogue. C/D mapping: col = lane&15, row = (lane>>4)*4 + j.
  const size_t zoff = (MODE == 2) ? (size_t)blockIdx.z * N_TOK * ldc : 0;
#pragma unroll
  for (int m = 0; m < 8; ++m) {
#pragma unroll
    for (int n = 0; n < 4; ++n) {
#pragma unroll
      for (int j = 0; j < 4; ++j) {
        int row = rowBlk + wr + m * 16 + (lane >> 4) * 4 + j;
        int col = colBlk + wc + n * 16 + fr;
        float v = acc[m][n][j];
        if (MODE == 0) {
          v += bias[col];
          if (col < 1024) v *= 0.125f;  // fold 1/sqrt(DK) into q
          ((half_t*)Cout)[(size_t)row * ldc + col] = (half_t)v;
        } else if (MODE == 1) {
          ((half_t*)Cout)[(size_t)row * ldc + col] = (half_t)v;
        } else {
          ((half_t*)Cout)[zoff + (size_t)row * ldc + col] = (half_t)v;
        }
      }
    }
  }
}

// ---------------------------------------------------------------------------
// 2-phase 128x128 GEMM — used for the small vwT GEMM only.
// ---------------------------------------------------------------------------
template <int ROWS>
DEVI void stage32(const half_t* __restrict__ g, int ld, half_t* lbase, int tid) {
#pragma unroll
  for (int c = tid; c < ROWS * 4; c += 256) {
    int r = c >> 2;
    int k8 = ((c & 3) ^ ((r >> 1) & 3)) * 8;
    gld_lds16(g + (size_t)r * ld + k8, lbase + c * 8);
  }
}

__launch_bounds__(256, 2)
__global__ void gemm2(const half_t* __restrict__ A, int lda,
                      const half_t* __restrict__ B, int ldb,
                      half_t* __restrict__ Cout, int ldc, int K) {
  constexpr int BM = 128, BN = 128, MF = 4, NF = 4;
  __shared__ half_t At[2][BM * 32];
  __shared__ half_t Bt[2][BN * 32];

  const int tid = threadIdx.x;
  const int lane = tid & 63;
  const int wid = tid >> 6;

  const int nx = gridDim.x;
  const int nwg = nx * gridDim.y;
  const int bid = blockIdx.y * nx + blockIdx.x;
  const int cpx = nwg >> 3;
  const int swz = (bid & 7) * cpx + (bid >> 3);
  const int rowBlk = (swz / nx) * BM;
  const int colBlk = (swz % nx) * BN;

  const int wr = (wid >> 1) * (BM / 2);
  const int wc = (wid & 1) * (BN / 2);
  const int fr = lane & 15;
  const int fs = lane >> 4;

  const half_t* Ag = A + (size_t)rowBlk * lda;
  const half_t* Bg = B + (size_t)colBlk * ldb;

  f32x4 acc[MF][NF] = {};
  const int NT = K >> 5;
  stage32<BM>(Ag, lda, At[0], tid);
  stage32<BN>(Bg, ldb, Bt[0], tid);
  __syncthreads();

  int cur = 0;
  for (int t = 0; t < NT; ++t) {
    if (t + 1 < NT) {
      stage32<BM>(Ag + (t + 1) * 32, lda, At[cur ^ 1], tid);
      stage32<BN>(Bg + (t + 1) * 32, ldb, Bt[cur ^ 1], tid);
    }
    const half_t* Ac = At[cur];
    const half_t* Bc = Bt[cur];
    half8 af[MF], bf[NF];
#pragma unroll
    for (int m = 0; m < MF; ++m) {
      int row = wr + m * 16 + fr;
      af[m] = *(const half8*)(Ac + row * 32 + ((fs ^ ((row >> 1) & 3)) * 8));
    }
#pragma unroll
    for (int n = 0; n < NF; ++n) {
      int row = wc + n * 16 + fr;
      bf[n] = *(const half8*)(Bc + row * 32 + ((fs ^ ((row >> 1) & 3)) * 8));
    }
#pragma unroll
    for (int m = 0; m < MF; ++m)
#pragma unroll
      for (int n = 0; n < NF; ++n)
        acc[m][n] = MFMA(af[m], bf[n], acc[m][n]);
    __syncthreads();
    cur ^= 1;
  }

#pragma unroll
  for (int m = 0; m < MF; ++m)
#pragma unroll
    for (int n = 0; n < NF; ++n)
#pragma unroll
      for (int j = 0; j < 4; ++j) {
        int row = rowBlk + wr + m * 16 + (lane >> 4) * 4 + j;
        int col = colBlk + wc + n * 16 + fr;
        Cout[(size_t)row * ldc + col] = (half_t)acc[m][n][j];
      }
}

// ---------------------------------------------------------------------------
// Split-K reduce: out = sum of 4 fp16 partials + bias (f32 out). 8 elems/thread.
// ---------------------------------------------------------------------------
__launch_bounds__(256)
__global__ void reduce_bias4(const half_t* __restrict__ p, const float* __restrict__ bias,
                             float* __restrict__ out) {
  int i = blockIdx.x * 256 + threadIdx.x;  // half8 index
  const size_t stride8 = (size_t)N_TOK * LATENT / 8;
  half8 a = ((const half8*)p)[i];
  half8 b = ((const half8*)p)[i + stride8];
  half8 c = ((const half8*)p)[i + 2 * stride8];
  half8 d = ((const half8*)p)[i + 3 * stride8];
  float4 e0 = ((const float4*)bias)[(i & 127) * 2];
  float4 e1 = ((const float4*)bias)[(i & 127) * 2 + 1];
  float r[8];
#pragma unroll
  for (int j = 0; j < 8; ++j)
    r[j] = (float)a[j] + (float)b[j] + (float)c[j] + (float)d[j];
  float4 o0, o1;
  o0.x = r[0] + e0.x; o0.y = r[1] + e0.y; o0.z = r[2] + e0.z; o0.w = r[3] + e0.w;
  o1.x = r[4] + e1.x; o1.y = r[5] + e1.y; o1.z = r[6] + e1.z; o1.w = r[7] + e1.w;
  ((float4*)out)[i * 2] = o0;
  ((float4*)out)[i * 2 + 1] = o1;
}

// ---------------------------------------------------------------------------
// Row softmax: S fp16 [4096][4096] -> P fp16. One block (256 thr) per row.
// ---------------------------------------------------------------------------
__launch_bounds__(256)
__global__ void softmax_rows(const half_t* __restrict__ S, half_t* __restrict__ P) {
  const int row = blockIdx.x;
  const int t = threadIdx.x;
  const half8* s8 = (const half8*)(S + (size_t)row * N_TOK);

  half8 v[2];
  float lmax = -1e30f;
#pragma unroll
  for (int i = 0; i < 2; ++i) {
    v[i] = s8[t + i * 256];
#pragma unroll
    for (int j = 0; j < 8; ++j) lmax = fmaxf(lmax, (float)v[i][j]);
  }
#pragma unroll
  for (int off = 32; off; off >>= 1) lmax = fmaxf(lmax, __shfl_xor(lmax, off));

  __shared__ float redm[4];
  __shared__ float reds[4];
  if ((t & 63) == 0) redm[t >> 6] = lmax;
  __syncthreads();
  lmax = fmaxf(fmaxf(redm[0], redm[1]), fmaxf(redm[2], redm[3]));

  float e[16];
  float lsum = 0.f;
#pragma unroll
  for (int i = 0; i < 2; ++i)
#pragma unroll
    for (int j = 0; j < 8; ++j) {
      float ev = __expf((float)v[i][j] - lmax);
      e[i * 8 + j] = ev;
      lsum += ev;
    }
#pragma unroll
  for (int off = 32; off; off >>= 1) lsum += __shfl_xor(lsum, off);
  if ((t & 63) == 0) reds[t >> 6] = lsum;
  __syncthreads();
  float inv = 1.f / (reds[0] + reds[1] + reds[2] + reds[3]);

  half8* p8 = (half8*)(P + (size_t)row * N_TOK);
#pragma unroll
  for (int i = 0; i < 2; ++i) {
    half8 h;
#pragma unroll
    for (int j = 0; j < 8; ++j) h[j] = (half_t)(e[i * 8 + j] * inv);
    p8[t + i * 256] = h;
  }
}

// ---------------------------------------------------------------------------
// Transpose [R][C] -> fp16 [C][R].
// ---------------------------------------------------------------------------
template <typename TI>
__global__ void transpose_to_f16(const TI* __restrict__ in, int ldin,
                                 half_t* __restrict__ out, int ldout) {
  __shared__ float tile[32][33];
  const int cb = blockIdx.x * 32;
  const int rb = blockIdx.y * 32;
  const int tx = threadIdx.x;
#pragma unroll
  for (int i = threadIdx.y; i < 32; i += 8)
    tile[i][tx] = (float)in[(size_t)(rb + i) * ldin + cb + tx];
  __syncthreads();
#pragma unroll
  for (int i = threadIdx.y; i < 32; i += 8)
    out[(size_t)(cb + i) * ldout + rb + tx] = (half_t)tile[tx][i];
}

__global__ void cvt_f32_f16(const float* __restrict__ in, half_t* __restrict__ out) {
  int i = blockIdx.x * 256 + threadIdx.x;
  float4 v = ((const float4*)in)[i];
  half4 h;
  h[0] = (half_t)v.x; h[1] = (half_t)v.y; h[2] = (half_t)v.z; h[3] = (half_t)v.w;
  ((half4*)out)[i] = h;
}

extern "C" void kernel_launch(void* const* d_in, const int* in_sizes, int n_in,
                              void* d_out, int out_size, void* d_ws, size_t ws_size,
                              hipStream_t stream) {
  const float* x = (const float*)d_in[0];
  const float* w_qkv = (const float*)d_in[1];
  const float* b_qkv = (const float*)d_in[2];
  const float* w_out = (const float*)d_in[3];
  const float* b_out = (const float*)d_in[4];
  float* out = (float*)d_out;

  char* ws = (char*)d_ws;
  half_t* xb    = (half_t*)(ws);
  half_t* wqkvT = (half_t*)(ws + ((size_t)8 << 20));
  half_t* qkv   = (half_t*)(ws + ((size_t)14 << 20));
  half_t* S     = (half_t*)(ws + ((size_t)46 << 20));
  half_t* P     = (half_t*)(ws + ((size_t)78 << 20));
  half_t* vwT   = (half_t*)(ws + ((size_t)118 << 20));
  half_t* woutT = (half_t*)(ws + ((size_t)126 << 20));
  half_t* parts = (half_t*)(ws + ((size_t)14 << 20));  // qkv+S dead by then; 32 MB

  dim3 tb(32, 8);

  // 1. x -> fp16
  cvt_f32_f16<<<(N_TOK * LATENT) / (256 * 4), 256, 0, stream>>>(x, xb);
  // 2. w_qkv -> wqkvT [3072][1024] fp16
  transpose_to_f16<float><<<dim3(QKVN / 32, LATENT / 32), tb, 0, stream>>>(w_qkv, QKVN, wqkvT, LATENT);
  // 3. w_out -> woutT [1024][1024] fp16
  transpose_to_f16<float><<<dim3(LATENT / 32, LATENT / 32), tb, 0, stream>>>(w_out, LATENT, woutT, LATENT);
  // 4. qkv = x @ w_qkv + b (q scaled 0.125)  (192 blocks @ 256x256)
  gemm8<0><<<dim3(QKVN / 256, N_TOK / 256), 512, 0, stream>>>(
      xb, LATENT, wqkvT, LATENT, qkv, QKVN, b_qkv, LATENT);
  // 5. vwT[i][j] = sum_k woutT[i][k] * v[j][k]  (256 blocks @ 128x128)
  gemm2<<<dim3(N_TOK / 128, LATENT / 128), 256, 0, stream>>>(
      woutT, LATENT, qkv + 2 * LATENT, QKVN, vwT, N_TOK, LATENT);
  // 6. S = q' @ k^T  (256 blocks @ 256x256)
  gemm8<1><<<dim3(N_TOK / 256, N_TOK / 256), 512, 0, stream>>>(
      qkv, QKVN, qkv + LATENT, QKVN, S, N_TOK, nullptr, LATENT);
  // 7. P = softmax rows
  softmax_rows<<<N_TOK, 256, 0, stream>>>(S, P);
  // 8. parts = P @ vwT, split-K=4, fp16 partials  (4 x 64 blocks @ 256x256)
  gemm8<2><<<dim3(LATENT / 256, N_TOK / 256, 4), 512, 0, stream>>>(
      P, N_TOK, vwT, N_TOK, parts, LATENT, nullptr, 1024);
  // 9. out = sum(parts) + b_out
  reduce_bias4<<<(N_TOK * LATENT) / (256 * 8), 256, 0, stream>>>(parts, b_out, out);
}